// Round 3
// baseline (407.845 us; speedup 1.0000x reference)
//
#include <hip/hip_runtime.h>
#include <hip/hip_bf16.h>

// ---- problem constants ----
#define BB 512
#define SS 49
#define DD 448
#define HH 8
#define QKVO 1536
#define MLPH 1792
#define MM (BB*SS)          // 25088 rows

using bf16_t = __hip_bfloat16;
typedef __attribute__((ext_vector_type(8))) short short8;   // bf16x8 MFMA frag
typedef __attribute__((ext_vector_type(4))) float f32x4;    // MFMA acc

__device__ __forceinline__ void gload_lds16(const void* g, void* l) {
  __builtin_amdgcn_global_load_lds(
      (const __attribute__((address_space(1))) void*)g,
      (__attribute__((address_space(3))) void*)l,
      16, 0, 0);
}

// ---------------- LDS-tiled transpose+cast: dst[C][R] bf16 = src[R][C] f32 ----------------
__global__ __launch_bounds__(256) void transpose_cast(const float* __restrict__ src,
                                                      bf16_t* __restrict__ dst,
                                                      int R, int C)
{
  __shared__ float tile[32][33];
  const int tx = threadIdx.x & 31, ty = threadIdx.x >> 5;   // ty 0..7
  const int c0 = blockIdx.x * 32, r0 = blockIdx.y * 32;
#pragma unroll
  for (int i = 0; i < 4; ++i)
    tile[ty + i*8][tx] = src[(size_t)(r0 + ty + i*8) * C + c0 + tx];
  __syncthreads();
#pragma unroll
  for (int i = 0; i < 4; ++i)
    dst[(size_t)(c0 + ty + i*8) * R + r0 + tx] = __float2bfloat16(tile[tx][ty + i*8]);
}

// ---------------- bias table expand to padded [8][64][64] bf16 ----------------
__global__ __launch_bounds__(256) void biasprep_kernel(const float* __restrict__ ab,
                                                       const int* __restrict__ idxs,
                                                       bf16_t* __restrict__ bias_pad)
{
  int idx = blockIdx.x * 256 + threadIdx.x;   // 32768
  int h = idx >> 12, r = (idx >> 6) & 63, c = idx & 63;
  float v = (r < SS && c < SS) ? ab[h*49 + idxs[r*49 + c]] : -1e30f;
  bias_pad[idx] = __float2bfloat16(v);
}

// ---------------- layernorm: one wave per row of 448 ----------------
__global__ __launch_bounds__(256) void ln_kernel(const float* __restrict__ x,
                                                 const float* __restrict__ g,
                                                 const float* __restrict__ b,
                                                 bf16_t* __restrict__ out)
{
  const int w = threadIdx.x >> 6, lane = threadIdx.x & 63;
  const int row = blockIdx.x * 4 + w;
  const float* xr = x + (size_t)row * DD;
  float v[7];
  float s = 0.f;
#pragma unroll
  for (int j = 0; j < 7; ++j) { v[j] = xr[lane + 64*j]; s += v[j]; }
#pragma unroll
  for (int off = 32; off; off >>= 1) s += __shfl_xor(s, off, 64);
  const float mu = s * (1.0f/448.0f);
  float q = 0.f;
#pragma unroll
  for (int j = 0; j < 7; ++j) { float d = v[j] - mu; q += d*d; }
#pragma unroll
  for (int off = 32; off; off >>= 1) q += __shfl_xor(q, off, 64);
  const float rstd = rsqrtf(q * (1.0f/448.0f) + 1e-5f);
  bf16_t* orow = out + (size_t)row * DD;
#pragma unroll
  for (int j = 0; j < 7; ++j) {
    int c = lane + 64*j;
    orow[c] = __float2bfloat16((v[j] - mu) * rstd * g[c] + b[c]);
  }
}

// ---------------- 256x256 8-wave counted-vmcnt GEMM: C = A(MxK) @ Bt(NxK)^T ----------------
// BK=32 K-tiles in a ring-4 LDS (128 KiB), stage 2 tiles ahead, 2 phases/tile,
// raw s_barrier (no vmcnt drain), one counted vmcnt(4) per tile. LDS chunk
// swizzle: phys_chunk = fq ^ (r&3) ^ ((r>>2)&1)  (frag reads hit 8 distinct
// bank-quads, 2 lanes each = conflict-free; staging is linear via
// pre-swizzled global source).
enum { EP_BF16 = 0, EP_RES1 = 1, EP_GELU = 2, EP_RES2 = 3 };

#define MFMA_ROW(mi, areg) \
  acc[mi][0] = __builtin_amdgcn_mfma_f32_16x16x32_bf16(areg, b0, acc[mi][0], 0, 0, 0); \
  acc[mi][1] = __builtin_amdgcn_mfma_f32_16x16x32_bf16(areg, b1, acc[mi][1], 0, 0, 0); \
  acc[mi][2] = __builtin_amdgcn_mfma_f32_16x16x32_bf16(areg, b2, acc[mi][2], 0, 0, 0); \
  acc[mi][3] = __builtin_amdgcn_mfma_f32_16x16x32_bf16(areg, b3, acc[mi][3], 0, 0, 0);

template<int EPI>
__global__ __launch_bounds__(512, 2) void gemm8_bf16(
    const bf16_t* __restrict__ A, const bf16_t* __restrict__ Bt,
    const float* __restrict__ bias, const float* __restrict__ resid,
    const float* __restrict__ ls, bf16_t* __restrict__ Obf,
    float* __restrict__ Of, int N, int K)
{
  extern __shared__ char lds[];          // 4 slots x 32KB: A[256][32] + B[256][32]
  const int t = threadIdx.x;
  const int lane = t & 63;
  const int w = t >> 6;                  // 0..7
  const int wm = w >> 2, wn = w & 3;
  const int m0 = blockIdx.x * 256;
  const int n0 = blockIdx.y * 256;
  const int NT = K >> 5;

  // frag-read addressing
  const int fr = lane & 15, g = lane >> 4;
  const int xs = (g ^ (fr & 3) ^ ((fr >> 2) & 1)) << 4;
  const int fro = fr * 64 + xs;

  // staging addressing (4 gloads/thread/tile: A rows 0-127, B rows 0-127, A 128-255, B 128-255)
  const int r0s = w * 16 + (lane >> 2);       // 0..127
  const int cc = lane & 3;
  const int fq = cc ^ ((r0s & 3) ^ ((r0s >> 2) & 1));
  const size_t gA0 = (size_t)(m0 + r0s) * K + fq * 8;
  const size_t gA1 = gA0 + (size_t)128 * K;
  int nb0 = n0 + r0s;       if (nb0 > N - 1) nb0 = N - 1;
  int nb1 = n0 + 128 + r0s; if (nb1 > N - 1) nb1 = N - 1;
  const size_t gB0 = (size_t)nb0 * K + fq * 8;
  const size_t gB1 = (size_t)nb1 * K + fq * 8;
  const int ldsw = w * 1024;

  f32x4 acc[8][4];
#pragma unroll
  for (int i = 0; i < 8; ++i)
#pragma unroll
    for (int j = 0; j < 4; ++j)
      acc[i][j] = f32x4{0.f, 0.f, 0.f, 0.f};

  // ---- prologue: stage tiles 0 and 1 (8 loads/thread) ----
#pragma unroll
  for (int T = 0; T < 2; ++T) {
    char* sb = lds + T * 32768;
    gload_lds16(A  + gA0 + T*32, sb + ldsw);
    gload_lds16(Bt + gB0 + T*32, sb + 16384 + ldsw);
    gload_lds16(A  + gA1 + T*32, sb + 8192 + ldsw);
    gload_lds16(Bt + gB1 + T*32, sb + 16384 + 8192 + ldsw);
  }
  asm volatile("s_waitcnt vmcnt(4)" ::: "memory");   // tile 0 landed
  __builtin_amdgcn_sched_barrier(0);
  __builtin_amdgcn_s_barrier();
  __builtin_amdgcn_sched_barrier(0);

  for (int T = 0; T < NT; ++T) {
    const char* sb = lds + (T & 3) * 32768;
    const char* sA = sb + wm * 8192 + fro;
    const char* sB = sb + 16384 + wn * 4096 + fro;
    const bool st = (T + 2 < NT);
    const size_t ko = (size_t)(T + 2) * 32;
    char* db = lds + ((T + 2) & 3) * 32768;

    // ---------- phase A: m-frags 0-3 ----------
    short8 a0 = *(const short8*)(sA);
    short8 a1 = *(const short8*)(sA + 1024);
    short8 a2 = *(const short8*)(sA + 2048);
    short8 a3 = *(const short8*)(sA + 3072);
    short8 b0 = *(const short8*)(sB);
    short8 b1 = *(const short8*)(sB + 1024);
    short8 b2 = *(const short8*)(sB + 2048);
    short8 b3 = *(const short8*)(sB + 3072);
    if (st) {
      gload_lds16(A  + gA0 + ko, db + ldsw);
      gload_lds16(Bt + gB0 + ko, db + 16384 + ldsw);
    }
    __builtin_amdgcn_sched_barrier(0);
    __builtin_amdgcn_s_barrier();
    asm volatile("s_waitcnt lgkmcnt(0)" ::: "memory");
    __builtin_amdgcn_sched_barrier(0);
    __builtin_amdgcn_s_setprio(1);
    MFMA_ROW(0, a0)
    MFMA_ROW(1, a1)
    MFMA_ROW(2, a2)
    MFMA_ROW(3, a3)
    __builtin_amdgcn_s_setprio(0);
    __builtin_amdgcn_sched_barrier(0);
    __builtin_amdgcn_s_barrier();
    __builtin_amdgcn_sched_barrier(0);

    // ---------- phase B: m-frags 4-7 ----------
    a0 = *(const short8*)(sA + 4096);
    a1 = *(const short8*)(sA + 5120);
    a2 = *(const short8*)(sA + 6144);
    a3 = *(const short8*)(sA + 7168);
    if (st) {
      gload_lds16(A  + gA1 + ko, db + 8192 + ldsw);
      gload_lds16(Bt + gB1 + ko, db + 16384 + 8192 + ldsw);
    }
    __builtin_amdgcn_sched_barrier(0);
    __builtin_amdgcn_s_barrier();
    asm volatile("s_waitcnt lgkmcnt(0)" ::: "memory");
    __builtin_amdgcn_sched_barrier(0);
    __builtin_amdgcn_s_setprio(1);
    MFMA_ROW(4, a0)
    MFMA_ROW(5, a1)
    MFMA_ROW(6, a2)
    MFMA_ROW(7, a3)
    __builtin_amdgcn_s_setprio(0);
    __builtin_amdgcn_sched_barrier(0);
    if (st) { asm volatile("s_waitcnt vmcnt(4)" ::: "memory"); }  // tile T+1 landed
    else    { asm volatile("s_waitcnt vmcnt(0)" ::: "memory"); }
    __builtin_amdgcn_s_barrier();
    __builtin_amdgcn_sched_barrier(0);
  }

  // ---------- epilogue: col = lane&15, row = g*4 + ri ----------
#pragma unroll
  for (int mi = 0; mi < 8; ++mi) {
#pragma unroll
    for (int ni = 0; ni < 4; ++ni) {
      const int col = n0 + wn*64 + ni*16 + fr;
      if (col < N) {
        const float bc = bias[col];
        const int row0 = m0 + wm*128 + mi*16 + g*4;
#pragma unroll
        for (int ri = 0; ri < 4; ++ri) {
          const size_t o = (size_t)(row0 + ri) * N + col;
          const float v = acc[mi][ni][ri] + bc;
          if constexpr (EPI == EP_BF16) {
            Obf[o] = __float2bfloat16(v);
          } else if constexpr (EPI == EP_GELU) {
            Obf[o] = __float2bfloat16(0.5f * v * (1.0f + erff(v * 0.7071067811865475f)));
          } else if constexpr (EPI == EP_RES1) {
            Of[o] = resid[o] + ls[col] * v;
          } else { // EP_RES2
            Of[o] = Of[o] + ls[col] * v;
          }
        }
      }
    }
  }
}

// ---------------- attention via MFMA: one wave per (b,h) ----------------
__global__ __launch_bounds__(64) void attn_mfma_kernel(const bf16_t* __restrict__ qkv,
                                                       const bf16_t* __restrict__ bias_pad,
                                                       bf16_t* __restrict__ ctx)
{
  __shared__ __align__(16) bf16_t VsF[64*128];
  __shared__ __align__(16) bf16_t PsF[64*72];
  const int b = blockIdx.x >> 3, h = blockIdx.x & 7;
  const int l = threadIdx.x;
  const int fr = l & 15, g = l >> 4;
  const size_t base = ((size_t)b * SS) * QKVO + (size_t)h * 192;

  // stage V (rows >= 49 duplicate row 48: finite, and P there is exactly 0)
  for (int c = l; c < 1024; c += 64) {
    const int j = c >> 4, ch = c & 15;
    const int jc = j < SS ? j : SS - 1;
    short8 v = *(const short8*)(qkv + base + (size_t)jc * QKVO + 64 + ch*8);
    *(short8*)(&VsF[j*128 + ((ch ^ (j >> 3)) & 15)*8]) = v;
  }

  // QK^T: fragments straight from global (row-major [s][32] == frag layout)
  short8 qf[4], kf[4];
#pragma unroll
  for (int mi = 0; mi < 4; ++mi) {
    int qr = mi*16 + fr; if (qr > SS-1) qr = SS-1;
    qf[mi] = *(const short8*)(qkv + base + (size_t)qr * QKVO + g*8);
    int kr = mi*16 + fr; if (kr > SS-1) kr = SS-1;
    kf[mi] = *(const short8*)(qkv + base + (size_t)kr * QKVO + 32 + g*8);
  }
  f32x4 sc[4][4];
#pragma unroll
  for (int mi = 0; mi < 4; ++mi)
#pragma unroll
    for (int ni = 0; ni < 4; ++ni)
      sc[mi][ni] = f32x4{0.f,0.f,0.f,0.f};
#pragma unroll
  for (int mi = 0; mi < 4; ++mi)
#pragma unroll
    for (int ni = 0; ni < 4; ++ni)
      sc[mi][ni] = __builtin_amdgcn_mfma_f32_16x16x32_bf16(qf[mi], kf[ni], sc[mi][ni], 0, 0, 0);

  // scale + bias + row softmax (rows live in 16-lane groups)
  const float scale = 0.17677669529663687f;   // 32^-0.5
  const bf16_t* bp = bias_pad + (size_t)h * 4096;
#pragma unroll
  for (int mi = 0; mi < 4; ++mi) {
#pragma unroll
    for (int ri = 0; ri < 4; ++ri) {
      const int r = mi*16 + g*4 + ri;
      float v0 = sc[mi][0][ri]*scale + __bfloat162float(bp[r*64 +      fr]);
      float v1 = sc[mi][1][ri]*scale + __bfloat162float(bp[r*64 + 16 + fr]);
      float v2 = sc[mi][2][ri]*scale + __bfloat162float(bp[r*64 + 32 + fr]);
      float v3 = sc[mi][3][ri]*scale + __bfloat162float(bp[r*64 + 48 + fr]);
      float m = fmaxf(fmaxf(v0, v1), fmaxf(v2, v3));
#pragma unroll
      for (int off = 8; off; off >>= 1) m = fmaxf(m, __shfl_xor(m, off, 64));
      v0 = __expf(v0 - m); v1 = __expf(v1 - m);
      v2 = __expf(v2 - m); v3 = __expf(v3 - m);
      float s = v0 + v1 + v2 + v3;
#pragma unroll
      for (int off = 8; off; off >>= 1) s += __shfl_xor(s, off, 64);
      const float inv = 1.0f / s;
      PsF[r*72 +      fr] = __float2bfloat16(v0 * inv);
      PsF[r*72 + 16 + fr] = __float2bfloat16(v1 * inv);
      PsF[r*72 + 32 + fr] = __float2bfloat16(v2 * inv);
      PsF[r*72 + 48 + fr] = __float2bfloat16(v3 * inv);
    }
  }
  __syncthreads();

  // PV: A = P (LDS b128 frags), B = V (swizzled scalar gather)
  short8 pf[4][2];
#pragma unroll
  for (int mi = 0; mi < 4; ++mi)
#pragma unroll
    for (int ks = 0; ks < 2; ++ks)
      pf[mi][ks] = *(const short8*)(&PsF[(mi*16 + fr)*72 + ks*32 + g*8]);

#pragma unroll
  for (int ni = 0; ni < 8; ++ni) {
    const int e = ni*16 + fr;
    short8 vf[2];
#pragma unroll
    for (int ks = 0; ks < 2; ++ks) {
      const int jb = ks*32 + g*8;
#pragma unroll
      for (int jj = 0; jj < 8; ++jj) {
        const int j = jb + jj;
        const int ch = ((e >> 3) ^ (j >> 3)) & 15;
        vf[ks][jj] = *(const short*)(&VsF[j*128 + ch*8 + (e & 7)]);
      }
    }
    f32x4 acc2[4];
#pragma unroll
    for (int mi = 0; mi < 4; ++mi) acc2[mi] = f32x4{0.f,0.f,0.f,0.f};
#pragma unroll
    for (int ks = 0; ks < 2; ++ks)
#pragma unroll
      for (int mi = 0; mi < 4; ++mi)
        acc2[mi] = __builtin_amdgcn_mfma_f32_16x16x32_bf16(pf[mi][ks], vf[ks], acc2[mi], 0, 0, 0);
#pragma unroll
    for (int mi = 0; mi < 4; ++mi) {
#pragma unroll
      for (int ri = 0; ri < 4; ++ri) {
        const int q = mi*16 + g*4 + ri;
        if (q < SS)
          ctx[((size_t)b * SS + q) * 1024 + h*128 + e] = __float2bfloat16(acc2[mi][ri]);
      }
    }
  }
}

// ---------------- launch ----------------
extern "C" void kernel_launch(void* const* d_in, const int* in_sizes, int n_in,
                              void* d_out, int out_size, void* d_ws, size_t ws_size,
                              hipStream_t stream) {
  const float* x      = (const float*)d_in[0];
  const float* ln1_g  = (const float*)d_in[1];
  const float* ln1_b  = (const float*)d_in[2];
  const float* qkv_w  = (const float*)d_in[3];
  const float* qkv_b  = (const float*)d_in[4];
  const float* ab     = (const float*)d_in[5];
  const float* proj_w = (const float*)d_in[6];
  const float* proj_b = (const float*)d_in[7];
  const float* ln2_g  = (const float*)d_in[8];
  const float* ln2_b  = (const float*)d_in[9];
  const float* w1     = (const float*)d_in[10];
  const float* b1     = (const float*)d_in[11];
  const float* w2     = (const float*)d_in[12];
  const float* b2     = (const float*)d_in[13];
  const float* ls1    = (const float*)d_in[14];
  const float* ls2    = (const float*)d_in[15];
  const int*   idxs   = (const int*)d_in[16];
  float* out = (float*)d_out;
  char* ws = (char*)d_ws;

  // workspace layout (bytes, 256-aligned) — same footprint as round 1/2
  bf16_t* h_buf    = (bf16_t*)(ws);                       // 22,478,848
  bf16_t* qkv_buf  = (bf16_t*)(ws + 22478848);            // 77,070,336
  bf16_t* ctx_buf  = (bf16_t*)(ws + 99549184);            // 51,380,224
  bf16_t* m_buf    = (bf16_t*)(ws + 22478848);            // 89,915,392 (overlay qkv+ctx)
  bf16_t* qkv_wT   = (bf16_t*)(ws + 150929408);           // 1536x448
  bf16_t* proj_wT  = (bf16_t*)(ws + 152305664);           // 448x1024
  bf16_t* w1T      = (bf16_t*)(ws + 153223168);           // 1792x448
  bf16_t* w2T      = (bf16_t*)(ws + 154828800);           // 448x1792
  bf16_t* bias_pad = (bf16_t*)(ws + 156434432);           // 65,536 -> end 156,499,968

  hipFuncSetAttribute((const void*)&gemm8_bf16<EP_BF16>, hipFuncAttributeMaxDynamicSharedMemorySize, 131072);
  hipFuncSetAttribute((const void*)&gemm8_bf16<EP_RES1>, hipFuncAttributeMaxDynamicSharedMemorySize, 131072);
  hipFuncSetAttribute((const void*)&gemm8_bf16<EP_GELU>, hipFuncAttributeMaxDynamicSharedMemorySize, 131072);
  hipFuncSetAttribute((const void*)&gemm8_bf16<EP_RES2>, hipFuncAttributeMaxDynamicSharedMemorySize, 131072);

  transpose_cast<<<dim3(QKVO/32, DD/32),  256, 0, stream>>>(qkv_w,  qkv_wT,  DD,   QKVO);
  transpose_cast<<<dim3(DD/32, 1024/32),  256, 0, stream>>>(proj_w, proj_wT, 1024, DD);
  transpose_cast<<<dim3(MLPH/32, DD/32),  256, 0, stream>>>(w1,     w1T,     DD,   MLPH);
  transpose_cast<<<dim3(DD/32, MLPH/32),  256, 0, stream>>>(w2,     w2T,     MLPH, DD);
  biasprep_kernel<<<128, 256, 0, stream>>>(ab, idxs, bias_pad);

  ln_kernel<<<MM/4, 256, 0, stream>>>(x, ln1_g, ln1_b, h_buf);

  gemm8_bf16<EP_BF16><<<dim3(MM/256, QKVO/256), 512, 131072, stream>>>(
      h_buf, qkv_wT, qkv_b, nullptr, nullptr, qkv_buf, nullptr, QKVO, DD);

  attn_mfma_kernel<<<BB*HH, 64, 0, stream>>>(qkv_buf, bias_pad, ctx_buf);

  gemm8_bf16<EP_RES1><<<dim3(MM/256, 2), 512, 131072, stream>>>(
      ctx_buf, proj_wT, proj_b, x, ls1, nullptr, out, DD, 1024);

  ln_kernel<<<MM/4, 256, 0, stream>>>(out, ln2_g, ln2_b, h_buf);

  gemm8_bf16<EP_GELU><<<dim3(MM/256, MLPH/256), 512, 131072, stream>>>(
      h_buf, w1T, b1, nullptr, nullptr, m_buf, nullptr, MLPH, DD);

  gemm8_bf16<EP_RES2><<<dim3(MM/256, 2), 512, 131072, stream>>>(
      m_buf, w2T, b2, nullptr, ls2, nullptr, out, DD, MLPH);
}

// Round 4
// 400.158 us; speedup vs baseline: 1.0192x; 1.0192x over previous
//
#include <hip/hip_runtime.h>
#include <hip/hip_bf16.h>

// ---- problem constants ----
#define BB 512
#define SS 49
#define DD 448
#define HH 8
#define QKVO 1536
#define MLPH 1792
#define MM (BB*SS)          // 25088 rows

using bf16_t = __hip_bfloat16;
typedef __attribute__((ext_vector_type(8))) short short8;   // bf16x8 MFMA frag
typedef __attribute__((ext_vector_type(4))) float f32x4;    // MFMA acc

__device__ __forceinline__ void gload_lds16(const void* g, void* l) {
  __builtin_amdgcn_global_load_lds(
      (const __attribute__((address_space(1))) void*)g,
      (__attribute__((address_space(3))) void*)l,
      16, 0, 0);
}

// ---------------- LDS-tiled transpose+cast: dst[C][R] bf16 = src[R][C] f32 ----------------
__global__ __launch_bounds__(256) void transpose_cast(const float* __restrict__ src,
                                                      bf16_t* __restrict__ dst,
                                                      int R, int C)
{
  __shared__ float tile[32][33];
  const int tx = threadIdx.x & 31, ty = threadIdx.x >> 5;   // ty 0..7
  const int c0 = blockIdx.x * 32, r0 = blockIdx.y * 32;
#pragma unroll
  for (int i = 0; i < 4; ++i)
    tile[ty + i*8][tx] = src[(size_t)(r0 + ty + i*8) * C + c0 + tx];
  __syncthreads();
#pragma unroll
  for (int i = 0; i < 4; ++i)
    dst[(size_t)(c0 + ty + i*8) * R + r0 + tx] = __float2bfloat16(tile[tx][ty + i*8]);
}

// ---------------- bias table expand to padded [8][64][64] bf16 ----------------
__global__ __launch_bounds__(256) void biasprep_kernel(const float* __restrict__ ab,
                                                       const int* __restrict__ idxs,
                                                       bf16_t* __restrict__ bias_pad)
{
  int idx = blockIdx.x * 256 + threadIdx.x;   // 32768
  int h = idx >> 12, r = (idx >> 6) & 63, c = idx & 63;
  float v = (r < SS && c < SS) ? ab[h*49 + idxs[r*49 + c]] : -1e30f;
  bias_pad[idx] = __float2bfloat16(v);
}

// ---------------- layernorm: one wave per row of 448 ----------------
__global__ __launch_bounds__(256) void ln_kernel(const float* __restrict__ x,
                                                 const float* __restrict__ g,
                                                 const float* __restrict__ b,
                                                 bf16_t* __restrict__ out)
{
  const int w = threadIdx.x >> 6, lane = threadIdx.x & 63;
  const int row = blockIdx.x * 4 + w;
  const float* xr = x + (size_t)row * DD;
  float v[7];
  float s = 0.f;
#pragma unroll
  for (int j = 0; j < 7; ++j) { v[j] = xr[lane + 64*j]; s += v[j]; }
#pragma unroll
  for (int off = 32; off; off >>= 1) s += __shfl_xor(s, off, 64);
  const float mu = s * (1.0f/448.0f);
  float q = 0.f;
#pragma unroll
  for (int j = 0; j < 7; ++j) { float d = v[j] - mu; q += d*d; }
#pragma unroll
  for (int off = 32; off; off >>= 1) q += __shfl_xor(q, off, 64);
  const float rstd = rsqrtf(q * (1.0f/448.0f) + 1e-5f);
  bf16_t* orow = out + (size_t)row * DD;
#pragma unroll
  for (int j = 0; j < 7; ++j) {
    int c = lane + 64*j;
    orow[c] = __float2bfloat16((v[j] - mu) * rstd * g[c] + b[c]);
  }
}

// ---------------- 128x128 4-wave ring-3 counted-vmcnt GEMM: C = A(MxK) @ Bt(NxK)^T ----------------
// BK=32, ring-3 LDS slots of 16KB (A[128][32] + B[128][32]), stage 2 tiles
// ahead with global_load_lds, one vmcnt(4) + one s_barrier per K-step.
// 48KB LDS + launch_bounds(256,3) -> 3 blocks/CU for cross-block overlap.
// Chunk swizzle: phys = g ^ (r&3) ^ ((r>>2)&1) (conflict-free b128 frag reads;
// staging linear via pre-swizzled global source).
enum { EP_BF16 = 0, EP_RES1 = 1, EP_GELU = 2, EP_RES2 = 3 };

template<int EPI>
__global__ __launch_bounds__(256, 3) void gemmp_bf16(
    const bf16_t* __restrict__ A, const bf16_t* __restrict__ Bt,
    const float* __restrict__ bias, const float* __restrict__ resid,
    const float* __restrict__ ls, bf16_t* __restrict__ Obf,
    float* __restrict__ Of, int N, int K)
{
  __shared__ __align__(16) char lds[49152];   // 3 slots x (A 8KB + B 8KB)
  const int t = threadIdx.x;
  const int lane = t & 63;
  const int w = t >> 6;                       // 0..3
  const int m0 = blockIdx.x * 128;
  const int n0 = blockIdx.y * 128;
  const int NT = K >> 5;
  const int fr = lane & 15, g = lane >> 4;
  const int wm = (w >> 1) * 64, wn = (w & 1) * 64;
  const int xs = (g ^ (fr & 3) ^ ((fr >> 2) & 1)) << 4;   // swizzled chunk byte off

  // frag-read offsets within a slot (loop-invariant)
  int aoff[4], boff[4];
#pragma unroll
  for (int i = 0; i < 4; ++i) {
    aoff[i] = (wm + i*16 + fr) * 64 + xs;
    boff[i] = 8192 + (wn + i*16 + fr) * 64 + xs;
  }

  // staging source addresses (per-lane, pre-swizzled): issue i covers rows i*64..i*64+63
  const int p = t & 3;
  const bf16_t* srcA[2];
  const bf16_t* srcB[2];
#pragma unroll
  for (int i = 0; i < 2; ++i) {
    const int r = i*64 + (t >> 2);
    const int l = p ^ (r & 3) ^ ((r >> 2) & 1);
    srcA[i] = A + (size_t)(m0 + r) * K + l*8;
    int rb = n0 + r; if (rb > N - 1) rb = N - 1;
    srcB[i] = Bt + (size_t)rb * K + l*8;
  }
  const int wb = w * 1024;                    // wave-uniform LDS sub-base

  f32x4 acc[4][4];
#pragma unroll
  for (int i = 0; i < 4; ++i)
#pragma unroll
    for (int j = 0; j < 4; ++j)
      acc[i][j] = f32x4{0.f, 0.f, 0.f, 0.f};

  // ---- prologue: stage tiles 0,1 (8 loads/thread total) ----
#pragma unroll
  for (int T = 0; T < 2; ++T) {
    char* sb = lds + T * 16384;
    gload_lds16(srcA[0] + T*32, sb + wb);
    gload_lds16(srcA[1] + T*32, sb + 4096 + wb);
    gload_lds16(srcB[0] + T*32, sb + 8192 + wb);
    gload_lds16(srcB[1] + T*32, sb + 12288 + wb);
  }
  asm volatile("s_waitcnt vmcnt(4)" ::: "memory");   // tile 0 landed
  __builtin_amdgcn_sched_barrier(0);
  asm volatile("s_barrier" ::: "memory");
  __builtin_amdgcn_sched_barrier(0);

  int sl = 0;
  for (int T = 0; T < NT; ++T) {
    const char* sb = lds + sl * 16384;
    const bool st = (T + 2 < NT);
    if (st) {
      int sl2 = sl + 2; if (sl2 >= 3) sl2 -= 3;
      char* db = lds + sl2 * 16384;
      const int ko = (T + 2) * 32;
      gload_lds16(srcA[0] + ko, db + wb);
      gload_lds16(srcA[1] + ko, db + 4096 + wb);
      gload_lds16(srcB[0] + ko, db + 8192 + wb);
      gload_lds16(srcB[1] + ko, db + 12288 + wb);
    }
    short8 af[4], bf_[4];
#pragma unroll
    for (int i = 0; i < 4; ++i) {
      af[i]  = *(const short8*)(sb + aoff[i]);
      bf_[i] = *(const short8*)(sb + boff[i]);
    }
    __builtin_amdgcn_s_setprio(1);
#pragma unroll
    for (int mi = 0; mi < 4; ++mi)
#pragma unroll
      for (int ni = 0; ni < 4; ++ni)
        acc[mi][ni] = __builtin_amdgcn_mfma_f32_16x16x32_bf16(af[mi], bf_[ni], acc[mi][ni], 0, 0, 0);
    __builtin_amdgcn_s_setprio(0);
    __builtin_amdgcn_sched_barrier(0);
    if (st) { asm volatile("s_waitcnt vmcnt(4)" ::: "memory"); }  // tile T+1 landed
    else    { asm volatile("s_waitcnt vmcnt(0)" ::: "memory"); }
    asm volatile("s_barrier" ::: "memory");
    __builtin_amdgcn_sched_barrier(0);
    sl = (sl + 1 == 3) ? 0 : sl + 1;
  }

  // ---- epilogue: D col = lane&15, row = g*4 + ri ----
#pragma unroll
  for (int mi = 0; mi < 4; ++mi) {
#pragma unroll
    for (int ni = 0; ni < 4; ++ni) {
      const int col = n0 + wn + ni*16 + fr;
      if (col < N) {
        const float bc = bias[col];
        const int row0 = m0 + wm + mi*16 + g*4;
#pragma unroll
        for (int ri = 0; ri < 4; ++ri) {
          const size_t o = (size_t)(row0 + ri) * N + col;
          const float v = acc[mi][ni][ri] + bc;
          if constexpr (EPI == EP_BF16) {
            Obf[o] = __float2bfloat16(v);
          } else if constexpr (EPI == EP_GELU) {
            Obf[o] = __float2bfloat16(0.5f * v * (1.0f + erff(v * 0.7071067811865475f)));
          } else if constexpr (EPI == EP_RES1) {
            Of[o] = resid[o] + ls[col] * v;
          } else { // EP_RES2
            Of[o] = Of[o] + ls[col] * v;
          }
        }
      }
    }
  }
}

// ---------------- attention via MFMA: one wave per (b,h) ----------------
__global__ __launch_bounds__(64) void attn_mfma_kernel(const bf16_t* __restrict__ qkv,
                                                       const bf16_t* __restrict__ bias_pad,
                                                       bf16_t* __restrict__ ctx)
{
  __shared__ __align__(16) bf16_t VsF[64*128];
  __shared__ __align__(16) bf16_t PsF[64*72];
  const int b = blockIdx.x >> 3, h = blockIdx.x & 7;
  const int l = threadIdx.x;
  const int fr = l & 15, g = l >> 4;
  const size_t base = ((size_t)b * SS) * QKVO + (size_t)h * 192;

  // stage V (rows >= 49 duplicate row 48: finite, and P there is exactly 0)
  for (int c = l; c < 1024; c += 64) {
    const int j = c >> 4, ch = c & 15;
    const int jc = j < SS ? j : SS - 1;
    short8 v = *(const short8*)(qkv + base + (size_t)jc * QKVO + 64 + ch*8);
    *(short8*)(&VsF[j*128 + ((ch ^ (j >> 3)) & 15)*8]) = v;
  }

  // QK^T: fragments straight from global (row-major [s][32] == frag layout)
  short8 qf[4], kf[4];
#pragma unroll
  for (int mi = 0; mi < 4; ++mi) {
    int qr = mi*16 + fr; if (qr > SS-1) qr = SS-1;
    qf[mi] = *(const short8*)(qkv + base + (size_t)qr * QKVO + g*8);
    int kr = mi*16 + fr; if (kr > SS-1) kr = SS-1;
    kf[mi] = *(const short8*)(qkv + base + (size_t)kr * QKVO + 32 + g*8);
  }
  f32x4 sc[4][4];
#pragma unroll
  for (int mi = 0; mi < 4; ++mi)
#pragma unroll
    for (int ni = 0; ni < 4; ++ni)
      sc[mi][ni] = f32x4{0.f,0.f,0.f,0.f};
#pragma unroll
  for (int mi = 0; mi < 4; ++mi)
#pragma unroll
    for (int ni = 0; ni < 4; ++ni)
      sc[mi][ni] = __builtin_amdgcn_mfma_f32_16x16x32_bf16(qf[mi], kf[ni], sc[mi][ni], 0, 0, 0);

  // scale + bias + row softmax (rows live in 16-lane groups)
  const float scale = 0.17677669529663687f;   // 32^-0.5
  const bf16_t* bp = bias_pad + (size_t)h * 4096;
#pragma unroll
  for (int mi = 0; mi < 4; ++mi) {
#pragma unroll
    for (int ri = 0; ri < 4; ++ri) {
      const int r = mi*16 + g*4 + ri;
      float v0 = sc[mi][0][ri]*scale + __bfloat162float(bp[r*64 +      fr]);
      float v1 = sc[mi][1][ri]*scale + __bfloat162float(bp[r*64 + 16 + fr]);
      float v2 = sc[mi][2][ri]*scale + __bfloat162float(bp[r*64 + 32 + fr]);
      float v3 = sc[mi][3][ri]*scale + __bfloat162float(bp[r*64 + 48 + fr]);
      float m = fmaxf(fmaxf(v0, v1), fmaxf(v2, v3));
#pragma unroll
      for (int off = 8; off; off >>= 1) m = fmaxf(m, __shfl_xor(m, off, 64));
      v0 = __expf(v0 - m); v1 = __expf(v1 - m);
      v2 = __expf(v2 - m); v3 = __expf(v3 - m);
      float s = v0 + v1 + v2 + v3;
#pragma unroll
      for (int off = 8; off; off >>= 1) s += __shfl_xor(s, off, 64);
      const float inv = 1.0f / s;
      PsF[r*72 +      fr] = __float2bfloat16(v0 * inv);
      PsF[r*72 + 16 + fr] = __float2bfloat16(v1 * inv);
      PsF[r*72 + 32 + fr] = __float2bfloat16(v2 * inv);
      PsF[r*72 + 48 + fr] = __float2bfloat16(v3 * inv);
    }
  }
  __syncthreads();

  // PV: A = P (LDS b128 frags), B = V (swizzled scalar gather)
  short8 pf[4][2];
#pragma unroll
  for (int mi = 0; mi < 4; ++mi)
#pragma unroll
    for (int ks = 0; ks < 2; ++ks)
      pf[mi][ks] = *(const short8*)(&PsF[(mi*16 + fr)*72 + ks*32 + g*8]);

#pragma unroll
  for (int ni = 0; ni < 8; ++ni) {
    const int e = ni*16 + fr;
    short8 vf[2];
#pragma unroll
    for (int ks = 0; ks < 2; ++ks) {
      const int jb = ks*32 + g*8;
#pragma unroll
      for (int jj = 0; jj < 8; ++jj) {
        const int j = jb + jj;
        const int ch = ((e >> 3) ^ (j >> 3)) & 15;
        vf[ks][jj] = *(const short*)(&VsF[j*128 + ch*8 + (e & 7)]);
      }
    }
    f32x4 acc2[4];
#pragma unroll
    for (int mi = 0; mi < 4; ++mi) acc2[mi] = f32x4{0.f,0.f,0.f,0.f};
#pragma unroll
    for (int ks = 0; ks < 2; ++ks)
#pragma unroll
      for (int mi = 0; mi < 4; ++mi)
        acc2[mi] = __builtin_amdgcn_mfma_f32_16x16x32_bf16(pf[mi][ks], vf[ks], acc2[mi], 0, 0, 0);
#pragma unroll
    for (int mi = 0; mi < 4; ++mi) {
#pragma unroll
      for (int ri = 0; ri < 4; ++ri) {
        const int q = mi*16 + g*4 + ri;
        if (q < SS)
          ctx[((size_t)b * SS + q) * 1024 + h*128 + e] = __float2bfloat16(acc2[mi][ri]);
      }
    }
  }
}

// ---------------- launch ----------------
extern "C" void kernel_launch(void* const* d_in, const int* in_sizes, int n_in,
                              void* d_out, int out_size, void* d_ws, size_t ws_size,
                              hipStream_t stream) {
  const float* x      = (const float*)d_in[0];
  const float* ln1_g  = (const float*)d_in[1];
  const float* ln1_b  = (const float*)d_in[2];
  const float* qkv_w  = (const float*)d_in[3];
  const float* qkv_b  = (const float*)d_in[4];
  const float* ab     = (const float*)d_in[5];
  const float* proj_w = (const float*)d_in[6];
  const float* proj_b = (const float*)d_in[7];
  const float* ln2_g  = (const float*)d_in[8];
  const float* ln2_b  = (const float*)d_in[9];
  const float* w1     = (const float*)d_in[10];
  const float* b1     = (const float*)d_in[11];
  const float* w2     = (const float*)d_in[12];
  const float* b2     = (const float*)d_in[13];
  const float* ls1    = (const float*)d_in[14];
  const float* ls2    = (const float*)d_in[15];
  const int*   idxs   = (const int*)d_in[16];
  float* out = (float*)d_out;
  char* ws = (char*)d_ws;

  // workspace layout (bytes, 256-aligned)
  bf16_t* h_buf    = (bf16_t*)(ws);                       // 22,478,848
  bf16_t* qkv_buf  = (bf16_t*)(ws + 22478848);            // 77,070,336
  bf16_t* ctx_buf  = (bf16_t*)(ws + 99549184);            // 51,380,224
  bf16_t* m_buf    = (bf16_t*)(ws + 22478848);            // 89,915,392 (overlay qkv+ctx)
  bf16_t* qkv_wT   = (bf16_t*)(ws + 150929408);           // 1536x448
  bf16_t* proj_wT  = (bf16_t*)(ws + 152305664);           // 448x1024
  bf16_t* w1T      = (bf16_t*)(ws + 153223168);           // 1792x448
  bf16_t* w2T      = (bf16_t*)(ws + 154828800);           // 448x1792
  bf16_t* bias_pad = (bf16_t*)(ws + 156434432);           // 65,536 -> end 156,499,968

  transpose_cast<<<dim3(QKVO/32, DD/32),  256, 0, stream>>>(qkv_w,  qkv_wT,  DD,   QKVO);
  transpose_cast<<<dim3(DD/32, 1024/32),  256, 0, stream>>>(proj_w, proj_wT, 1024, DD);
  transpose_cast<<<dim3(MLPH/32, DD/32),  256, 0, stream>>>(w1,     w1T,     DD,   MLPH);
  transpose_cast<<<dim3(DD/32, MLPH/32),  256, 0, stream>>>(w2,     w2T,     MLPH, DD);
  biasprep_kernel<<<128, 256, 0, stream>>>(ab, idxs, bias_pad);

  ln_kernel<<<MM/4, 256, 0, stream>>>(x, ln1_g, ln1_b, h_buf);

  gemmp_bf16<EP_BF16><<<dim3(MM/128, QKVO/128), 256, 0, stream>>>(
      h_buf, qkv_wT, qkv_b, nullptr, nullptr, qkv_buf, nullptr, QKVO, DD);

  attn_mfma_kernel<<<BB*HH, 64, 0, stream>>>(qkv_buf, bias_pad, ctx_buf);

  gemmp_bf16<EP_RES1><<<dim3(MM/128, 4), 256, 0, stream>>>(
      ctx_buf, proj_wT, proj_b, x, ls1, nullptr, out, DD, 1024);

  ln_kernel<<<MM/4, 256, 0, stream>>>(out, ln2_g, ln2_b, h_buf);

  gemmp_bf16<EP_GELU><<<dim3(MM/128, MLPH/128), 256, 0, stream>>>(
      h_buf, w1T, b1, nullptr, nullptr, m_buf, nullptr, MLPH, DD);

  gemmp_bf16<EP_RES2><<<dim3(MM/128, 4), 256, 0, stream>>>(
      m_buf, w2T, b2, nullptr, ls2, nullptr, out, DD, MLPH);
}

// Round 6
// 324.391 us; speedup vs baseline: 1.2573x; 1.2336x over previous
//
#include <hip/hip_runtime.h>
#include <hip/hip_bf16.h>

// ---- problem constants ----
#define BB 512
#define SS 49
#define DD 448
#define HH 8
#define QKVO 1536
#define MLPH 1792
#define MM (BB*SS)          // 25088 rows

using bf16_t = __hip_bfloat16;
typedef __attribute__((ext_vector_type(8))) short short8;   // bf16x8 MFMA frag
typedef __attribute__((ext_vector_type(4))) float f32x4;    // MFMA acc

__device__ __forceinline__ void gload_lds16(const void* g, void* l) {
  __builtin_amdgcn_global_load_lds(
      (const __attribute__((address_space(1))) void*)g,
      (__attribute__((address_space(3))) void*)l,
      16, 0, 0);
}

// ---------------- LDS-tiled transpose+cast: dst[C][R] bf16 = src[R][C] f32 ----------------
__global__ __launch_bounds__(256) void transpose_cast(const float* __restrict__ src,
                                                      bf16_t* __restrict__ dst,
                                                      int R, int C)
{
  __shared__ float tile[32][33];
  const int tx = threadIdx.x & 31, ty = threadIdx.x >> 5;   // ty 0..7
  const int c0 = blockIdx.x * 32, r0 = blockIdx.y * 32;
#pragma unroll
  for (int i = 0; i < 4; ++i)
    tile[ty + i*8][tx] = src[(size_t)(r0 + ty + i*8) * C + c0 + tx];
  __syncthreads();
#pragma unroll
  for (int i = 0; i < 4; ++i)
    dst[(size_t)(c0 + ty + i*8) * R + r0 + tx] = __float2bfloat16(tile[tx][ty + i*8]);
}

// ---------------- bias table expand to padded [8][64][64] bf16 ----------------
__global__ __launch_bounds__(256) void biasprep_kernel(const float* __restrict__ ab,
                                                       const int* __restrict__ idxs,
                                                       bf16_t* __restrict__ bias_pad)
{
  int idx = blockIdx.x * 256 + threadIdx.x;   // 32768
  int h = idx >> 12, r = (idx >> 6) & 63, c = idx & 63;
  float v = (r < SS && c < SS) ? ab[h*49 + idxs[r*49 + c]] : -1e30f;
  bias_pad[idx] = __float2bfloat16(v);
}

// ---------------- layernorm: one wave per row of 448 ----------------
__global__ __launch_bounds__(256) void ln_kernel(const float* __restrict__ x,
                                                 const float* __restrict__ g,
                                                 const float* __restrict__ b,
                                                 bf16_t* __restrict__ out)
{
  const int w = threadIdx.x >> 6, lane = threadIdx.x & 63;
  const int row = blockIdx.x * 4 + w;
  const float* xr = x + (size_t)row * DD;
  float v[7];
  float s = 0.f;
#pragma unroll
  for (int j = 0; j < 7; ++j) { v[j] = xr[lane + 64*j]; s += v[j]; }
#pragma unroll
  for (int off = 32; off; off >>= 1) s += __shfl_xor(s, off, 64);
  const float mu = s * (1.0f/448.0f);
  float q = 0.f;
#pragma unroll
  for (int j = 0; j < 7; ++j) { float d = v[j] - mu; q += d*d; }
#pragma unroll
  for (int off = 32; off; off >>= 1) q += __shfl_xor(q, off, 64);
  const float rstd = rsqrtf(q * (1.0f/448.0f) + 1e-5f);
  bf16_t* orow = out + (size_t)row * DD;
#pragma unroll
  for (int j = 0; j < 7; ++j) {
    int c = lane + 64*j;
    orow[c] = __float2bfloat16((v[j] - mu) * rstd * g[c] + b[c]);
  }
}

// ---------------- BMx128 4-wave GEMM (R2-proven structure): C = A(MxK) @ Bt(NxK)^T ----------------
// BK=64 (one full 128B line per row per tile), single LDS buffer, 2 barriers
// per K-tile. 1D grid with bijective XCD chunk swizzle, n-fast decomposition
// (each XCD gets contiguous m-tiles with all their n-tiles -> A panel L2-local).
// BM=64 for skinny-N GEMMs doubles grid -> more co-resident blocks for
// latency hiding. Chunk-XOR swizzle on 16B chunks keeps frag reads conflict-free.
enum { EP_BF16 = 0, EP_RES1 = 1, EP_GELU = 2, EP_RES2 = 3 };

template<int EPI, int BM>
__global__ __launch_bounds__(256, 2) void gemmr_bf16(
    const bf16_t* __restrict__ A, const bf16_t* __restrict__ Bt,
    const float* __restrict__ bias, const float* __restrict__ resid,
    const float* __restrict__ ls, bf16_t* __restrict__ Obf,
    float* __restrict__ Of, int N, int K, int gy)
{
  constexpr int MI = BM / 32;            // m-frags per wave (4 or 2)
  constexpr int ABYTES = BM * 128;       // A tile bytes (BM x 64 bf16)
  __shared__ __align__(16) char lds[ABYTES + 16384];
  const int t = threadIdx.x;
  const int lane = t & 63;
  const int w = t >> 6;

  // XCD chunk swizzle (grid %8 == 0 guaranteed by launch)
  const int chunk = gridDim.x >> 3;
  const int lin = blockIdx.x;
  const int swz = (lin & 7) * chunk + (lin >> 3);
  const int m0 = (swz / gy) * BM;
  const int n0 = (swz % gy) * 128;

  const int fr = lane & 15;          // frag row (A) / col (B)
  const int fq = lane >> 4;          // k-quad
  const int wm = (w >> 1) * (BM / 2);
  const int wn = (w & 1) * 64;

  f32x4 acc[MI][4];
#pragma unroll
  for (int i = 0; i < MI; ++i)
#pragma unroll
    for (int j = 0; j < 4; ++j)
      acc[i][j] = f32x4{0.f, 0.f, 0.f, 0.f};

  // staging: issue i covers rows i*32..i*32+31; thread t -> row i*32+(t>>3), chunk t&7
  const int rsub = t >> 3;                   // 0..31
  const int g8 = (t & 7) ^ (rsub & 7);       // pre-swizzled global k-chunk
  const int wbase = w * 1024;                // wave-uniform LDS base
  const int nkt = K >> 6;

  for (int kt = 0; kt < nkt; ++kt) {
    const int k0 = kt << 6;
#pragma unroll
    for (int i = 0; i < MI; ++i)
      gload_lds16(A + (size_t)(m0 + i*32 + rsub) * K + (k0 + g8*8), lds + i*4096 + wbase);
#pragma unroll
    for (int i = 0; i < 4; ++i) {
      int rb = n0 + i*32 + rsub;
      if (rb >= N) rb = N - 1;               // clamp pad rows
      gload_lds16(Bt + (size_t)rb * K + (k0 + g8*8), lds + ABYTES + i*4096 + wbase);
    }
    __syncthreads();
#pragma unroll
    for (int kk = 0; kk < 2; ++kk) {
      short8 af[MI], bfr[4];
#pragma unroll
      for (int i = 0; i < MI; ++i) {
        const int ra = wm + i*16 + fr;
        const int ca = (fq + kk*4) ^ (ra & 7);
        af[i] = *(const short8*)(lds + ra*128 + ca*16);
      }
#pragma unroll
      for (int i = 0; i < 4; ++i) {
        const int rb2 = wn + i*16 + fr;
        const int cb = (fq + kk*4) ^ (rb2 & 7);
        bfr[i] = *(const short8*)(lds + ABYTES + rb2*128 + cb*16);
      }
#pragma unroll
      for (int mi = 0; mi < MI; ++mi)
#pragma unroll
        for (int ni = 0; ni < 4; ++ni)
          acc[mi][ni] = __builtin_amdgcn_mfma_f32_16x16x32_bf16(af[mi], bfr[ni], acc[mi][ni], 0, 0, 0);
    }
    __syncthreads();
  }

  // epilogue: D col = lane&15, row = fq*4 + ri
#pragma unroll
  for (int mi = 0; mi < MI; ++mi) {
#pragma unroll
    for (int ni = 0; ni < 4; ++ni) {
      const int col = n0 + wn + ni*16 + fr;
      if (col < N) {
        const float bc = bias[col];
        const int row0 = m0 + wm + mi*16 + fq*4;
#pragma unroll
        for (int ri = 0; ri < 4; ++ri) {
          const size_t o = (size_t)(row0 + ri) * N + col;
          const float v = acc[mi][ni][ri] + bc;
          if constexpr (EPI == EP_BF16) {
            Obf[o] = __float2bfloat16(v);
          } else if constexpr (EPI == EP_GELU) {
            Obf[o] = __float2bfloat16(0.5f * v * (1.0f + erff(v * 0.7071067811865475f)));
          } else if constexpr (EPI == EP_RES1) {
            Of[o] = resid[o] + ls[col] * v;
          } else { // EP_RES2
            Of[o] = Of[o] + ls[col] * v;
          }
        }
      }
    }
  }
}

// ---------------- attention via MFMA: one wave per (b,h) ----------------
__global__ __launch_bounds__(64) void attn_mfma_kernel(const bf16_t* __restrict__ qkv,
                                                       const bf16_t* __restrict__ bias_pad,
                                                       bf16_t* __restrict__ ctx)
{
  __shared__ __align__(16) bf16_t VsF[64*128];
  __shared__ __align__(16) bf16_t PsF[64*72];
  const int b = blockIdx.x >> 3, h = blockIdx.x & 7;
  const int l = threadIdx.x;
  const int fr = l & 15, g = l >> 4;
  const size_t base = ((size_t)b * SS) * QKVO + (size_t)h * 192;

  // stage V (rows >= 49 duplicate row 48: finite, and P there is exactly 0)
  for (int c = l; c < 1024; c += 64) {
    const int j = c >> 4, ch = c & 15;
    const int jc = j < SS ? j : SS - 1;
    short8 v = *(const short8*)(qkv + base + (size_t)jc * QKVO + 64 + ch*8);
    *(short8*)(&VsF[j*128 + ((ch ^ (j >> 3)) & 15)*8]) = v;
  }

  // QK^T: fragments straight from global (row-major [s][32] == frag layout)
  short8 qf[4], kf[4];
#pragma unroll
  for (int mi = 0; mi < 4; ++mi) {
    int qr = mi*16 + fr; if (qr > SS-1) qr = SS-1;
    qf[mi] = *(const short8*)(qkv + base + (size_t)qr * QKVO + g*8);
    int kr = mi*16 + fr; if (kr > SS-1) kr = SS-1;
    kf[mi] = *(const short8*)(qkv + base + (size_t)kr * QKVO + 32 + g*8);
  }
  f32x4 sc[4][4];
#pragma unroll
  for (int mi = 0; mi < 4; ++mi)
#pragma unroll
    for (int ni = 0; ni < 4; ++ni)
      sc[mi][ni] = f32x4{0.f,0.f,0.f,0.f};
#pragma unroll
  for (int mi = 0; mi < 4; ++mi)
#pragma unroll
    for (int ni = 0; ni < 4; ++ni)
      sc[mi][ni] = __builtin_amdgcn_mfma_f32_16x16x32_bf16(qf[mi], kf[ni], sc[mi][ni], 0, 0, 0);

  // scale + bias + row softmax (rows live in 16-lane groups)
  const float scale = 0.17677669529663687f;   // 32^-0.5
  const bf16_t* bp = bias_pad + (size_t)h * 4096;
#pragma unroll
  for (int mi = 0; mi < 4; ++mi) {
#pragma unroll
    for (int ri = 0; ri < 4; ++ri) {
      const int r = mi*16 + g*4 + ri;
      float v0 = sc[mi][0][ri]*scale + __bfloat162float(bp[r*64 +      fr]);
      float v1 = sc[mi][1][ri]*scale + __bfloat162float(bp[r*64 + 16 + fr]);
      float v2 = sc[mi][2][ri]*scale + __bfloat162float(bp[r*64 + 32 + fr]);
      float v3 = sc[mi][3][ri]*scale + __bfloat162float(bp[r*64 + 48 + fr]);
      float m = fmaxf(fmaxf(v0, v1), fmaxf(v2, v3));
#pragma unroll
      for (int off = 8; off; off >>= 1) m = fmaxf(m, __shfl_xor(m, off, 64));
      v0 = __expf(v0 - m); v1 = __expf(v1 - m);
      v2 = __expf(v2 - m); v3 = __expf(v3 - m);
      float s = v0 + v1 + v2 + v3;
#pragma unroll
      for (int off = 8; off; off >>= 1) s += __shfl_xor(s, off, 64);
      const float inv = 1.0f / s;
      PsF[r*72 +      fr] = __float2bfloat16(v0 * inv);
      PsF[r*72 + 16 + fr] = __float2bfloat16(v1 * inv);
      PsF[r*72 + 32 + fr] = __float2bfloat16(v2 * inv);
      PsF[r*72 + 48 + fr] = __float2bfloat16(v3 * inv);
    }
  }
  __syncthreads();

  // PV: A = P (LDS b128 frags), B = V (swizzled scalar gather)
  short8 pf[4][2];
#pragma unroll
  for (int mi = 0; mi < 4; ++mi)
#pragma unroll
    for (int ks = 0; ks < 2; ++ks)
      pf[mi][ks] = *(const short8*)(&PsF[(mi*16 + fr)*72 + ks*32 + g*8]);

#pragma unroll
  for (int ni = 0; ni < 8; ++ni) {
    const int e = ni*16 + fr;
    short8 vf[2];
#pragma unroll
    for (int ks = 0; ks < 2; ++ks) {
      const int jb = ks*32 + g*8;
#pragma unroll
      for (int jj = 0; jj < 8; ++jj) {
        const int j = jb + jj;
        const int ch = ((e >> 3) ^ (j >> 3)) & 15;
        vf[ks][jj] = *(const short*)(&VsF[j*128 + ch*8 + (e & 7)]);
      }
    }
    f32x4 acc2[4];
#pragma unroll
    for (int mi = 0; mi < 4; ++mi) acc2[mi] = f32x4{0.f,0.f,0.f,0.f};
#pragma unroll
    for (int ks = 0; ks < 2; ++ks)
#pragma unroll
      for (int mi = 0; mi < 4; ++mi)
        acc2[mi] = __builtin_amdgcn_mfma_f32_16x16x32_bf16(pf[mi][ks], vf[ks], acc2[mi], 0, 0, 0);
#pragma unroll
    for (int mi = 0; mi < 4; ++mi) {
#pragma unroll
      for (int ri = 0; ri < 4; ++ri) {
        const int q = mi*16 + g*4 + ri;
        if (q < SS)
          ctx[((size_t)b * SS + q) * 1024 + h*128 + e] = __float2bfloat16(acc2[mi][ri]);
      }
    }
  }
}

// ---------------- launch ----------------
extern "C" void kernel_launch(void* const* d_in, const int* in_sizes, int n_in,
                              void* d_out, int out_size, void* d_ws, size_t ws_size,
                              hipStream_t stream) {
  const float* x      = (const float*)d_in[0];
  const float* ln1_g  = (const float*)d_in[1];
  const float* ln1_b  = (const float*)d_in[2];
  const float* qkv_w  = (const float*)d_in[3];
  const float* qkv_b  = (const float*)d_in[4];
  const float* ab     = (const float*)d_in[5];
  const float* proj_w = (const float*)d_in[6];
  const float* proj_b = (const float*)d_in[7];
  const float* ln2_g  = (const float*)d_in[8];
  const float* ln2_b  = (const float*)d_in[9];
  const float* w1     = (const float*)d_in[10];
  const float* b1     = (const float*)d_in[11];
  const float* w2     = (const float*)d_in[12];
  const float* b2     = (const float*)d_in[13];
  const float* ls1    = (const float*)d_in[14];
  const float* ls2    = (const float*)d_in[15];
  const int*   idxs   = (const int*)d_in[16];
  float* out = (float*)d_out;
  char* ws = (char*)d_ws;

  // workspace layout (bytes, 256-aligned)
  bf16_t* h_buf    = (bf16_t*)(ws);                       // 22,478,848
  bf16_t* qkv_buf  = (bf16_t*)(ws + 22478848);            // 77,070,336
  bf16_t* ctx_buf  = (bf16_t*)(ws + 99549184);            // 51,380,224
  bf16_t* m_buf    = (bf16_t*)(ws + 22478848);            // 89,915,392 (overlay qkv+ctx)
  bf16_t* qkv_wT   = (bf16_t*)(ws + 150929408);           // 1536x448
  bf16_t* proj_wT  = (bf16_t*)(ws + 152305664);           // 448x1024
  bf16_t* w1T      = (bf16_t*)(ws + 153223168);           // 1792x448
  bf16_t* w2T      = (bf16_t*)(ws + 154828800);           // 448x1792
  bf16_t* bias_pad = (bf16_t*)(ws + 156434432);           // 65,536 -> end 156,499,968

  transpose_cast<<<dim3(QKVO/32, DD/32),  256, 0, stream>>>(qkv_w,  qkv_wT,  DD,   QKVO);
  transpose_cast<<<dim3(DD/32, 1024/32),  256, 0, stream>>>(proj_w, proj_wT, 1024, DD);
  transpose_cast<<<dim3(MLPH/32, DD/32),  256, 0, stream>>>(w1,     w1T,     DD,   MLPH);
  transpose_cast<<<dim3(DD/32, MLPH/32),  256, 0, stream>>>(w2,     w2T,     MLPH, DD);
  biasprep_kernel<<<128, 256, 0, stream>>>(ab, idxs, bias_pad);

  ln_kernel<<<MM/4, 256, 0, stream>>>(x, ln1_g, ln1_b, h_buf);

  // qkv: M=25088 (196x128), N=1536 (12), K=448
  gemmr_bf16<EP_BF16, 128><<<196*12, 256, 0, stream>>>(
      h_buf, qkv_wT, qkv_b, nullptr, nullptr, qkv_buf, nullptr, QKVO, DD, 12);

  attn_mfma_kernel<<<BB*HH, 64, 0, stream>>>(qkv_buf, bias_pad, ctx_buf);

  // proj: BM=64 (392 m-tiles), N=448 (4), K=1024
  gemmr_bf16<EP_RES1, 64><<<392*4, 256, 0, stream>>>(
      ctx_buf, proj_wT, proj_b, x, ls1, nullptr, out, DD, 1024, 4);

  ln_kernel<<<MM/4, 256, 0, stream>>>(out, ln2_g, ln2_b, h_buf);

  // mlp1: BM=128, N=1792 (14), K=448
  gemmr_bf16<EP_GELU, 128><<<196*14, 256, 0, stream>>>(
      h_buf, w1T, b1, nullptr, nullptr, m_buf, nullptr, MLPH, DD, 14);

  // mlp2: BM=64, N=448 (4), K=1792
  gemmr_bf16<EP_RES2, 64><<<392*4, 256, 0, stream>>>(
      m_buf, w2T, b2, nullptr, ls2, nullptr, out, DD, MLPH, 4);
}